// Round 16
// baseline (102.338 us; speedup 1.0000x reference)
//
#include <hip/hip_runtime.h>
#include <hip/hip_bf16.h>
#include <math.h>

#define TT 577          // real tokens per n
#define TP 640          // padded tokens per n
#define CCH 768         // channels
#define KR 64           // regions
#define NB 64           // batch

typedef __attribute__((ext_vector_type(8))) short bf16x8;
typedef __attribute__((ext_vector_type(8))) unsigned short ushort8;
typedef __attribute__((ext_vector_type(4))) float f32x4;

static constexpr float EPSF = 1e-12f;

static __device__ inline unsigned short f2bf(float f) {
    return __bfloat16_as_ushort(__float2bfloat16(f));
}

// ---------------------------------------------------------------------------
// Kernel 0: prep. (a) conv_w fp32 -> bf16 ws_w[64][768]; (b) zero ws_a row
// tails t in [592,640). Grid 24 x 256.
// ---------------------------------------------------------------------------
__global__ __launch_bounds__(256) void k_prep(
    const float* __restrict__ conv_w,
    unsigned short* __restrict__ ws_w,
    unsigned short* __restrict__ ws_a)
{
    const int g = blockIdx.x * 256 + threadIdx.x;   // [0, 6144)
    if (g < 6144) {
        const float* s = conv_w + (size_t)g * 8;
        float4 v0 = *reinterpret_cast<const float4*>(s);
        float4 v1 = *reinterpret_cast<const float4*>(s + 4);
        ushort8 o;
        o[0]=f2bf(v0.x); o[1]=f2bf(v0.y); o[2]=f2bf(v0.z); o[3]=f2bf(v0.w);
        o[4]=f2bf(v1.x); o[5]=f2bf(v1.y); o[6]=f2bf(v1.z); o[7]=f2bf(v1.w);
        *reinterpret_cast<ushort8*>(ws_w + (size_t)g * 8) = o;
    }
    if (g < 4096) {
        unsigned short* d = ws_a + (size_t)g * TP + 592;
        ushort8 z = {0,0,0,0,0,0,0,0};
        #pragma unroll
        for (int i = 0; i < 6; ++i)
            *reinterpret_cast<ushort8*>(d + i * 8) = z;
    }
}

// ---------------------------------------------------------------------------
// Kernel 1 v11 — the k_vlad template transplanted onto GEMM1:
// barrier-free K-loop, no LDS in the loop, named-register ping-pong,
// 256-thr blocks (4 waves x 16 tokens), W-frags b128 direct from L2-hot
// bf16 ws_w, X contiguous per-lane fp32, branch-free (token clamp; invalid
// tokens masked later via rsm=0). One __syncthreads total (epilogue).
// ---------------------------------------------------------------------------
#define LOADX(x0_,x1_, cc_)                                                    \
    x0_ = *reinterpret_cast<const float4*>(gsrc + (cc_));                      \
    x1_ = *reinterpret_cast<const float4*>(gsrc + (cc_) + 4);

#define LOADW(w0_,w1_,w2_,w3_, cc_)                                            \
    w0_ = *reinterpret_cast<const bf16x8*>(wbase +            (cc_));          \
    w1_ = *reinterpret_cast<const bf16x8*>(wbase + 16*CCH +   (cc_));          \
    w2_ = *reinterpret_cast<const bf16x8*>(wbase + 32*CCH +   (cc_));          \
    w3_ = *reinterpret_cast<const bf16x8*>(wbase + 48*CCH +   (cc_));

#define STEPL(x0_,x1_, w0_,w1_,w2_,w3_)                                        \
    {                                                                          \
        ss = fmaf(x0_.x,x0_.x, fmaf(x0_.y,x0_.y, fmaf(x0_.z,x0_.z,             \
             fmaf(x0_.w,x0_.w, fmaf(x1_.x,x1_.x, fmaf(x1_.y,x1_.y,             \
             fmaf(x1_.z,x1_.z, fmaf(x1_.w,x1_.w, ss))))))));                   \
        bf16x8 afrag;                                                          \
        ((unsigned short*)&afrag)[0] = f2bf(x0_.x);                            \
        ((unsigned short*)&afrag)[1] = f2bf(x0_.y);                            \
        ((unsigned short*)&afrag)[2] = f2bf(x0_.z);                            \
        ((unsigned short*)&afrag)[3] = f2bf(x0_.w);                            \
        ((unsigned short*)&afrag)[4] = f2bf(x1_.x);                            \
        ((unsigned short*)&afrag)[5] = f2bf(x1_.y);                            \
        ((unsigned short*)&afrag)[6] = f2bf(x1_.z);                            \
        ((unsigned short*)&afrag)[7] = f2bf(x1_.w);                            \
        acc[0] = __builtin_amdgcn_mfma_f32_16x16x32_bf16(afrag, w0_, acc[0], 0, 0, 0); \
        acc[1] = __builtin_amdgcn_mfma_f32_16x16x32_bf16(afrag, w1_, acc[1], 0, 0, 0); \
        acc[2] = __builtin_amdgcn_mfma_f32_16x16x32_bf16(afrag, w2_, acc[2], 0, 0, 0); \
        acc[3] = __builtin_amdgcn_mfma_f32_16x16x32_bf16(afrag, w3_, acc[3], 0, 0, 0); \
    }

__global__ __launch_bounds__(256, 4) void k_logits(
    const float* __restrict__ grids,
    const unsigned short* __restrict__ ws_w,
    const float* __restrict__ conv_b,
    unsigned short* __restrict__ ws_a,
    float* __restrict__ ws_asum)
{
    __shared__ __align__(16) unsigned short Abuf[4][KR * 24];  // 12.3 KB
    __shared__ float asum_lds[4][64];                          // 1 KB

    const int tid  = threadIdx.x;
    const int lane = tid & 63;
    const int w    = tid >> 6;
    // XCD-chunked bijective swizzle: 640 = 8 x 80
    const int b    = (blockIdx.x & 7) * 80 + (blockIdx.x >> 3);
    const int n    = b / 10;
    const int tb   = (b - n * 10) << 6;
    const int t0w  = tb + (w << 4);

    const int lr = lane & 15;
    const int lg = lane >> 4;

    const int tokA = t0w + lr;
    const int tokC = (tokA < TT) ? tokA : (TT - 1);    // branch-free clamp
    const float* gsrc = grids + ((size_t)n * TT + tokC) * CCH + (lg << 3);
    const unsigned short* wbase = ws_w + (size_t)lr * CCH + (lg << 3);

    f32x4 acc[4] = {};
    float ss = 0.f;

    float4 xa0, xa1, xb0, xb1;
    bf16x8 wa0, wa1, wa2, wa3, wb0, wb1, wb2, wb3;

    LOADX(xa0, xa1, 0)
    LOADW(wa0, wa1, wa2, wa3, 0)
    #pragma unroll
    for (int cp = 0; cp < 12; ++cp) {
        const int cc = cp << 6;                 // 0,64,...,704
        LOADX(xb0, xb1, cc + 32)
        LOADW(wb0, wb1, wb2, wb3, cc + 32)
        STEPL(xa0, xa1, wa0, wa1, wa2, wa3)
        if (cp < 11) {
            LOADX(xa0, xa1, cc + 64)
            LOADW(wa0, wa1, wa2, wa3, cc + 64)
        }
        STEPL(xb0, xb1, wb0, wb1, wb2, wb3)
    }

    // ---- token norm: reduce the 4 lg-groups of the same token ----
    ss += __shfl_xor(ss, 16);
    ss += __shfl_xor(ss, 32);
    const float nrm = sqrtf(ss);
    const float inv = 1.0f / fmaxf(nrm, EPSF);

    // ---- logits + softmax over 64 regions ----
    float b_[4];
    #pragma unroll
    for (int rt = 0; rt < 4; ++rt) b_[rt] = conv_b[rt*16 + lr];

    float invT[4];
    #pragma unroll
    for (int reg = 0; reg < 4; ++reg) invT[reg] = __shfl(inv, (lg << 2) + reg);

    float lgt[4][4], mx[4];
    #pragma unroll
    for (int reg = 0; reg < 4; ++reg) {
        float m = -1e30f;
        #pragma unroll
        for (int rt = 0; rt < 4; ++rt) {
            lgt[rt][reg] = fmaf(acc[rt][reg], invT[reg], b_[rt]);
            m = fmaxf(m, lgt[rt][reg]);
        }
        mx[reg] = m;
    }
    #pragma unroll
    for (int msk = 1; msk < 16; msk <<= 1) {
        #pragma unroll
        for (int reg = 0; reg < 4; ++reg) mx[reg] = fmaxf(mx[reg], __shfl_xor(mx[reg], msk));
    }
    float ex[4][4], sm[4] = {0.f, 0.f, 0.f, 0.f};
    #pragma unroll
    for (int rt = 0; rt < 4; ++rt) {
        #pragma unroll
        for (int reg = 0; reg < 4; ++reg) {
            ex[rt][reg] = __expf(lgt[rt][reg] - mx[reg]);
            sm[reg] += ex[rt][reg];
        }
    }
    #pragma unroll
    for (int msk = 1; msk < 16; msk <<= 1) {
        #pragma unroll
        for (int reg = 0; reg < 4; ++reg) sm[reg] += __shfl_xor(sm[reg], msk);
    }

    float rsm[4];
    #pragma unroll
    for (int reg = 0; reg < 4; ++reg) {
        const bool vt = (t0w + (lg << 2) + reg) < TT;   // masks clamped tokens
        rsm[reg] = vt ? (1.0f / sm[reg]) : 0.f;
    }

    // ---- per-block partial asum: pa[rt] holds kr = rt*16+lr ----
    float pa[4];
    #pragma unroll
    for (int rt = 0; rt < 4; ++rt) {
        pa[rt] = ex[rt][0]*rsm[0] + ex[rt][1]*rsm[1] + ex[rt][2]*rsm[2] + ex[rt][3]*rsm[3];
        pa[rt] += __shfl_xor(pa[rt], 16);
        pa[rt] += __shfl_xor(pa[rt], 32);
    }
    if (lane < 16) {
        #pragma unroll
        for (int rt = 0; rt < 4; ++rt)
            asum_lds[w][rt*16 + lane] = pa[rt];
    }

    // ---- a' = softmax * inv_norm, transposed via wave-private LDS ----
    #pragma unroll
    for (int reg = 0; reg < 4; ++reg) {
        const int trow = (lg << 2) + reg;
        const float scale = invT[reg] * rsm[reg];
        #pragma unroll
        for (int rt = 0; rt < 4; ++rt)
            Abuf[w][(rt*16 + lr)*24 + trow] = f2bf(ex[rt][reg] * scale);
    }
    __syncthreads();

    if (tid < 64)
        ws_asum[(size_t)b * 64 + tid] =
            asum_lds[0][tid] + asum_lds[1][tid] + asum_lds[2][tid] + asum_lds[3][tid];

    {
        ushort8 r0 = *reinterpret_cast<const ushort8*>(&Abuf[w][lane * 24]);
        ushort8 r1 = *reinterpret_cast<const ushort8*>(&Abuf[w][lane * 24 + 8]);
        unsigned short* dst = ws_a + ((size_t)n * KR + lane) * TP + t0w;
        *reinterpret_cast<ushort8*>(dst)     = r0;
        *reinterpret_cast<ushort8*>(dst + 8) = r1;
    }
}

// ---------------------------------------------------------------------------
// Kernel 2: GEMM2 (VLAD), R13 structure unchanged (XCD swizzle, fp32 B
// gathers from L3-resident grids, named ping-pong, barrier-free loop).
// ---------------------------------------------------------------------------
#define LOADA(d0,d1,d2,d3,t0_)                                                   \
    d0 = *reinterpret_cast<const bf16x8*>(abase +           (size_t)(t0_));      \
    d1 = *reinterpret_cast<const bf16x8*>(abase + 16*TP +   (size_t)(t0_));      \
    d2 = *reinterpret_cast<const bf16x8*>(abase + 32*TP +   (size_t)(t0_));      \
    d3 = *reinterpret_cast<const bf16x8*>(abase + 48*TP +   (size_t)(t0_));

#define LOADB(d,t0_) do {                                                        \
    const int tb2_ = (t0_) + (lg << 3);                                          \
    if ((t0_) + 32 <= TT) {                                                      \
        _Pragma("unroll")                                                        \
        for (int j_ = 0; j_ < 8; ++j_)                                           \
            ((unsigned short*)&(d))[j_] = f2bf(gb[(size_t)(tb2_ + j_) * CCH]);   \
    } else {                                                                     \
        _Pragma("unroll")                                                        \
        for (int j_ = 0; j_ < 8; ++j_) {                                         \
            float v_ = (tb2_ + j_ < TT) ? gb[(size_t)(tb2_ + j_) * CCH] : 0.f;   \
            ((unsigned short*)&(d))[j_] = f2bf(v_);                              \
        }                                                                        \
    } } while (0)

__global__ __launch_bounds__(256, 4) void k_vlad(
    const float* __restrict__ grids,
    const unsigned short* __restrict__ ws_a,
    const float* __restrict__ ws_asum,
    const float* __restrict__ centroids,
    float* __restrict__ out)
{
    __shared__ float asum_s[64];

    const int tid  = threadIdx.x;
    const int lane = tid & 63;
    const int w    = tid >> 6;
    const int b    = (blockIdx.x & 7) * 96 + (blockIdx.x >> 3);
    const int n    = b / 12;
    const int c0   = (b - n * 12) << 6;
    const int lr   = lane & 15;
    const int lg   = lane >> 4;

    if (tid < 64) {
        float s = 0.f;
        #pragma unroll
        for (int bb = 0; bb < 10; ++bb)
            s += ws_asum[((size_t)n * 10 + bb) * 64 + tid];
        asum_s[tid] = s;
    }
    __syncthreads();

    const int c = c0 + (w << 4) + lr;
    const unsigned short* abase = ws_a + ((size_t)n * KR + lr) * TP + (lg << 3);
    const float* gb = grids + (size_t)n * TT * CCH + c;

    f32x4 acc0 = {}, acc1 = {}, acc2 = {}, acc3 = {};
    bf16x8 a0, a1, a2, a3, b0;
    bf16x8 p0, p1, p2, p3, q0;

    LOADA(a0, a1, a2, a3, 0)
    LOADB(b0, 0);

    int t0 = 0;
    while (true) {
        int tn = t0 + 32;
        if (tn < TT) { LOADA(p0, p1, p2, p3, tn) LOADB(q0, tn); }
        acc0 = __builtin_amdgcn_mfma_f32_16x16x32_bf16(a0, b0, acc0, 0, 0, 0);
        acc1 = __builtin_amdgcn_mfma_f32_16x16x32_bf16(a1, b0, acc1, 0, 0, 0);
        acc2 = __builtin_amdgcn_mfma_f32_16x16x32_bf16(a2, b0, acc2, 0, 0, 0);
        acc3 = __builtin_amdgcn_mfma_f32_16x16x32_bf16(a3, b0, acc3, 0, 0, 0);
        t0 = tn;
        if (t0 >= TT) break;

        tn = t0 + 32;
        if (tn < TT) { LOADA(a0, a1, a2, a3, tn) LOADB(b0, tn); }
        acc0 = __builtin_amdgcn_mfma_f32_16x16x32_bf16(p0, q0, acc0, 0, 0, 0);
        acc1 = __builtin_amdgcn_mfma_f32_16x16x32_bf16(p1, q0, acc1, 0, 0, 0);
        acc2 = __builtin_amdgcn_mfma_f32_16x16x32_bf16(p2, q0, acc2, 0, 0, 0);
        acc3 = __builtin_amdgcn_mfma_f32_16x16x32_bf16(p3, q0, acc3, 0, 0, 0);
        t0 = tn;
        if (t0 >= TT) break;
    }

    #pragma unroll
    for (int reg = 0; reg < 4; ++reg) {
        {
            const int kr = 0*16 + (lg << 2) + reg;
            out[((size_t)n * KR + kr) * CCH + c] =
                acc0[reg] - asum_s[kr] * centroids[(size_t)kr * CCH + c];
        }
        {
            const int kr = 1*16 + (lg << 2) + reg;
            out[((size_t)n * KR + kr) * CCH + c] =
                acc1[reg] - asum_s[kr] * centroids[(size_t)kr * CCH + c];
        }
        {
            const int kr = 2*16 + (lg << 2) + reg;
            out[((size_t)n * KR + kr) * CCH + c] =
                acc2[reg] - asum_s[kr] * centroids[(size_t)kr * CCH + c];
        }
        {
            const int kr = 3*16 + (lg << 2) + reg;
            out[((size_t)n * KR + kr) * CCH + c] =
                acc3[reg] - asum_s[kr] * centroids[(size_t)kr * CCH + c];
        }
    }
}

// ---------------------------------------------------------------------------
// Kernel 3: 4 rows per 256-thr block; global L2 norm of 64 unit rows = 8.
// ---------------------------------------------------------------------------
__global__ __launch_bounds__(256) void kc_norm_kernel(float* __restrict__ out)
{
    const int tid = threadIdx.x;
    const int sub = tid >> 6;
    const int l   = tid & 63;
    float4* p = reinterpret_cast<float4*>(out) + ((size_t)blockIdx.x * 4 + sub) * 192;
    float4 v0 = p[l];
    float4 v1 = p[l + 64];
    float4 v2 = p[l + 128];
    float ss = v0.x*v0.x + v0.y*v0.y + v0.z*v0.z + v0.w*v0.w
             + v1.x*v1.x + v1.y*v1.y + v1.z*v1.z + v1.w*v1.w
             + v2.x*v2.x + v2.y*v2.y + v2.z*v2.z + v2.w*v2.w;
    #pragma unroll
    for (int m = 1; m < 64; m <<= 1) ss += __shfl_xor(ss, m);
    const float sc = 0.125f / fmaxf(sqrtf(ss), EPSF);
    v0.x*=sc; v0.y*=sc; v0.z*=sc; v0.w*=sc;
    v1.x*=sc; v1.y*=sc; v1.z*=sc; v1.w*=sc;
    v2.x*=sc; v2.y*=sc; v2.z*=sc; v2.w*=sc;
    p[l] = v0;
    p[l + 64] = v1;
    p[l + 128] = v2;
}

extern "C" void kernel_launch(void* const* d_in, const int* in_sizes, int n_in,
                              void* d_out, int out_size, void* d_ws, size_t ws_size,
                              hipStream_t stream)
{
    const float* grids     = (const float*)d_in[0];
    const float* conv_w    = (const float*)d_in[1];
    const float* conv_b    = (const float*)d_in[2];
    const float* centroids = (const float*)d_in[3];
    float* out = (float*)d_out;

    // ws layout (bytes):
    //   ws_a    [0,         5,242,880)   64*64*640 bf16
    //   ws_asum [5,242,880, 5,406,720)   640*64 f32
    //   ws_w    [5,406,720, 5,505,024)   64*768 bf16
    unsigned short* ws_a    = (unsigned short*)d_ws;
    float*          ws_asum = (float*)((char*)d_ws + 5242880);
    unsigned short* ws_w    = (unsigned short*)((char*)d_ws + 5406720);

    hipLaunchKernelGGL(k_prep, dim3(24), dim3(256), 0, stream,
                       conv_w, ws_w, ws_a);
    hipLaunchKernelGGL(k_logits, dim3(NB * 10), dim3(256), 0, stream,
                       grids, ws_w, conv_b, ws_a, ws_asum);
    hipLaunchKernelGGL(k_vlad, dim3(NB * 12), dim3(256), 0, stream,
                       grids, ws_a, ws_asum, centroids, out);
    hipLaunchKernelGGL(kc_norm_kernel, dim3(NB * KR / 4), dim3(256), 0, stream, out);
}

// Round 17
// 76.398 us; speedup vs baseline: 1.3395x; 1.3395x over previous
//
#include <hip/hip_runtime.h>
#include <hip/hip_bf16.h>
#include <math.h>

#define TT 577          // real tokens per n
#define TP 640          // padded tokens per n
#define CCH 768         // channels
#define KR 64           // regions
#define NB 64           // batch
#define CHK 64          // channels per K-chunk (12 chunks)

typedef __attribute__((ext_vector_type(8))) short bf16x8;
typedef __attribute__((ext_vector_type(8))) unsigned short ushort8;
typedef __attribute__((ext_vector_type(4))) float f32x4;

static constexpr float EPSF = 1e-12f;

static __device__ inline unsigned short f2bf(float f) {
    return __bfloat16_as_ushort(__float2bfloat16(f));
}

// async global->LDS, 16 B per lane, dest = wave-uniform base + lane*16
static __device__ __forceinline__ void gload_lds16(const void* gsrc, void* ldst) {
    __builtin_amdgcn_global_load_lds(
        (const __attribute__((address_space(1))) unsigned int*)gsrc,
        (__attribute__((address_space(3))) unsigned int*)ldst,
        16, 0, 0);
}

// ---------------------------------------------------------------------------
// Kernel 0: prep — conv_w fp32 -> bf16 ws_w[64][768]. Grid 24 x 256.
// ---------------------------------------------------------------------------
__global__ __launch_bounds__(256) void k_prep(
    const float* __restrict__ conv_w,
    unsigned short* __restrict__ ws_w)
{
    const int g = blockIdx.x * 256 + threadIdx.x;   // [0, 6144)
    if (g < 6144) {
        const float* s = conv_w + (size_t)g * 8;
        float4 v0 = *reinterpret_cast<const float4*>(s);
        float4 v1 = *reinterpret_cast<const float4*>(s + 4);
        ushort8 o;
        o[0]=f2bf(v0.x); o[1]=f2bf(v0.y); o[2]=f2bf(v0.z); o[3]=f2bf(v0.w);
        o[4]=f2bf(v1.x); o[5]=f2bf(v1.y); o[6]=f2bf(v1.z); o[7]=f2bf(v1.w);
        *reinterpret_cast<ushort8*>(ws_w + (size_t)g * 8) = o;
    }
}

// ---------------------------------------------------------------------------
// Kernel 1 v12 — m97 anatomy (FIRST use of global_load_lds in this session):
// GEMM1 + norm + softmax + a' transpose + partial asum.
// Grid 640 (XCD swizzle), 256 thr = 4 waves x 16 tokens.
// Per 64-c chunk: 6 async global_load_lds per wave (G fp32 4x1KB units,
// W bf16 2x1KB units) into LINEAR LDS with PRE-SWIZZLED global source
// (slot ^= row&7 -> bank-alias-free ds_reads), double-buffered, 1 barrier
// per chunk. No staged data in VGPRs -> no per-step waitcnt serialization
// (the mechanism behind R6-R16's ~66us floor; VGPR=56 smoking gun).
// ---------------------------------------------------------------------------
__global__ __launch_bounds__(256, 3) void k_logits(
    const float* __restrict__ grids,
    const unsigned short* __restrict__ ws_w,
    const float* __restrict__ conv_b,
    unsigned short* __restrict__ ws_a,
    float* __restrict__ ws_asum)
{
    __shared__ __align__(16) float          Gs[2][4096];   // 2 x 16 KB: [tok][64c] swz
    __shared__ __align__(16) unsigned short Wsh[2][4096];  // 2 x  8 KB: [kr][64c] swz

    const int tid  = threadIdx.x;
    const int lane = tid & 63;
    const int w    = tid >> 6;
    const int b    = (blockIdx.x & 7) * 80 + (blockIdx.x >> 3);   // 640 = 8x80
    const int n    = b / 10;
    const int tb   = (b - n * 10) << 6;
    const int t0w  = tb + (w << 4);

    const int lr = lane & 15;
    const int lg = lane >> 4;

    // ---- per-thread pre-swizzled global source pointers ----
    const float* gp0; const float* gp1; const float* gp2; const float* gp3;
    {
        const int sl = (lane & 15) >> 1, hf = lane & 1;
        #define GPINIT(gp_, i_)                                                \
        {   const int trow = (((w << 2) + (i_)) << 2) + (lane >> 4);           \
            const int tok  = (tb + trow < TT) ? (tb + trow) : (TT - 1);        \
            const int csw  = (((sl ^ (trow & 7)) << 3) + (hf << 2));           \
            gp_ = grids + ((size_t)n * TT + tok) * CCH + csw; }
        GPINIT(gp0, 0) GPINIT(gp1, 1) GPINIT(gp2, 2) GPINIT(gp3, 3)
        #undef GPINIT
    }
    const unsigned short* wp0; const unsigned short* wp1;
    {
        #define WPINIT(wp_, i_)                                                \
        {   const int row = (((w << 1) + (i_)) << 3) + (lane >> 3);            \
            const int csw = (((lane & 7) ^ (row & 7)) << 3);                   \
            wp_ = ws_w + (size_t)row * CCH + csw; }
        WPINIT(wp0, 0) WPINIT(wp1, 1)
        #undef WPINIT
    }

    #define STAGE(buf_)                                                        \
    {   gload_lds16(gp0, &Gs[buf_][(((w << 2) + 0) << 8)]);                    \
        gload_lds16(gp1, &Gs[buf_][(((w << 2) + 1) << 8)]);                    \
        gload_lds16(gp2, &Gs[buf_][(((w << 2) + 2) << 8)]);                    \
        gload_lds16(gp3, &Gs[buf_][(((w << 2) + 3) << 8)]);                    \
        gload_lds16(wp0, &Wsh[buf_][(((w << 1) + 0) << 9)]);                   \
        gload_lds16(wp1, &Wsh[buf_][(((w << 1) + 1) << 9)]);                   \
        gp0 += CHK; gp1 += CHK; gp2 += CHK; gp3 += CHK;                        \
        wp0 += CHK; wp1 += CHK; }

    f32x4 acc[4] = {};
    float ss = 0.f;
    const int tokL = (w << 4) + lr;          // LDS token row

    #define KSTEP2(buf_, s_)                                                   \
    {   const int sa = (((s_) << 2) + lg) ^ (tokL & 7);                        \
        const float* pg = &Gs[buf_][(tokL << 6) + (sa << 3)];                  \
        float4 u0 = *reinterpret_cast<const float4*>(pg);                      \
        float4 u1 = *reinterpret_cast<const float4*>(pg + 4);                  \
        ss = fmaf(u0.x,u0.x, fmaf(u0.y,u0.y, fmaf(u0.z,u0.z,                   \
             fmaf(u0.w,u0.w, fmaf(u1.x,u1.x, fmaf(u1.y,u1.y,                   \
             fmaf(u1.z,u1.z, fmaf(u1.w,u1.w, ss))))))));                       \
        bf16x8 af;                                                             \
        ((unsigned short*)&af)[0] = f2bf(u0.x);                                \
        ((unsigned short*)&af)[1] = f2bf(u0.y);                                \
        ((unsigned short*)&af)[2] = f2bf(u0.z);                                \
        ((unsigned short*)&af)[3] = f2bf(u0.w);                                \
        ((unsigned short*)&af)[4] = f2bf(u1.x);                                \
        ((unsigned short*)&af)[5] = f2bf(u1.y);                                \
        ((unsigned short*)&af)[6] = f2bf(u1.z);                                \
        ((unsigned short*)&af)[7] = f2bf(u1.w);                                \
        const int sw = (((s_) << 2) + lg) ^ (lr & 7);                          \
        bf16x8 b0 = *reinterpret_cast<const bf16x8*>(&Wsh[buf_][( lr       << 6) + (sw << 3)]); \
        bf16x8 b1 = *reinterpret_cast<const bf16x8*>(&Wsh[buf_][((16 + lr) << 6) + (sw << 3)]); \
        bf16x8 b2 = *reinterpret_cast<const bf16x8*>(&Wsh[buf_][((32 + lr) << 6) + (sw << 3)]); \
        bf16x8 b3 = *reinterpret_cast<const bf16x8*>(&Wsh[buf_][((48 + lr) << 6) + (sw << 3)]); \
        acc[0] = __builtin_amdgcn_mfma_f32_16x16x32_bf16(af, b0, acc[0], 0, 0, 0); \
        acc[1] = __builtin_amdgcn_mfma_f32_16x16x32_bf16(af, b1, acc[1], 0, 0, 0); \
        acc[2] = __builtin_amdgcn_mfma_f32_16x16x32_bf16(af, b2, acc[2], 0, 0, 0); \
        acc[3] = __builtin_amdgcn_mfma_f32_16x16x32_bf16(af, b3, acc[3], 0, 0, 0); }

    STAGE(0)
    __syncthreads();                          // drain chunk-0 loads

    #pragma unroll
    for (int ch = 0; ch < 12; ++ch) {
        if (ch < 11) STAGE((ch + 1) & 1)      // async; flies under compute
        KSTEP2(ch & 1, 0)
        KSTEP2(ch & 1, 1)
        __syncthreads();                      // drain next-chunk loads + RAW/WAR
    }

    // ---- token norm ----
    ss += __shfl_xor(ss, 16);
    ss += __shfl_xor(ss, 32);
    const float nrm = sqrtf(ss);
    const float inv = 1.0f / fmaxf(nrm, EPSF);

    // ---- logits + softmax over 64 regions ----
    float b_[4];
    #pragma unroll
    for (int rt = 0; rt < 4; ++rt) b_[rt] = conv_b[rt*16 + lr];

    float invT[4];
    #pragma unroll
    for (int reg = 0; reg < 4; ++reg) invT[reg] = __shfl(inv, (lg << 2) + reg);

    float lgt[4][4], mx[4];
    #pragma unroll
    for (int reg = 0; reg < 4; ++reg) {
        float m = -1e30f;
        #pragma unroll
        for (int rt = 0; rt < 4; ++rt) {
            lgt[rt][reg] = fmaf(acc[rt][reg], invT[reg], b_[rt]);
            m = fmaxf(m, lgt[rt][reg]);
        }
        mx[reg] = m;
    }
    #pragma unroll
    for (int msk = 1; msk < 16; msk <<= 1) {
        #pragma unroll
        for (int reg = 0; reg < 4; ++reg) mx[reg] = fmaxf(mx[reg], __shfl_xor(mx[reg], msk));
    }
    float ex[4][4], sm[4] = {0.f, 0.f, 0.f, 0.f};
    #pragma unroll
    for (int rt = 0; rt < 4; ++rt) {
        #pragma unroll
        for (int reg = 0; reg < 4; ++reg) {
            ex[rt][reg] = __expf(lgt[rt][reg] - mx[reg]);
            sm[reg] += ex[rt][reg];
        }
    }
    #pragma unroll
    for (int msk = 1; msk < 16; msk <<= 1) {
        #pragma unroll
        for (int reg = 0; reg < 4; ++reg) sm[reg] += __shfl_xor(sm[reg], msk);
    }

    float rsm[4];
    #pragma unroll
    for (int reg = 0; reg < 4; ++reg) {
        const bool vt = (t0w + (lg << 2) + reg) < TT;   // masks clamped tokens
        rsm[reg] = vt ? (1.0f / sm[reg]) : 0.f;
    }

    // ---- per-block partial asum (LDS aliased on Wsh[0], free after loop) ----
    float pa[4];
    #pragma unroll
    for (int rt = 0; rt < 4; ++rt) {
        pa[rt] = ex[rt][0]*rsm[0] + ex[rt][1]*rsm[1] + ex[rt][2]*rsm[2] + ex[rt][3]*rsm[3];
        pa[rt] += __shfl_xor(pa[rt], 16);
        pa[rt] += __shfl_xor(pa[rt], 32);
    }
    float* asum_lds = reinterpret_cast<float*>(&Wsh[0][0]);   // [4][64]
    if (lane < 16) {
        #pragma unroll
        for (int rt = 0; rt < 4; ++rt)
            asum_lds[(w << 6) + rt*16 + lane] = pa[rt];
    }

    // ---- a' transpose via LDS aliased on Gs[0] (free after loop) ----
    unsigned short* Abuf = reinterpret_cast<unsigned short*>(&Gs[0][0]) + (size_t)w * KR * 24;
    #pragma unroll
    for (int reg = 0; reg < 4; ++reg) {
        const int trow = (lg << 2) + reg;
        const float scale = invT[reg] * rsm[reg];
        #pragma unroll
        for (int rt = 0; rt < 4; ++rt)
            Abuf[(rt*16 + lr)*24 + trow] = f2bf(ex[rt][reg] * scale);
    }
    __syncthreads();

    if (tid < 64)
        ws_asum[(size_t)b * 64 + tid] =
            asum_lds[tid] + asum_lds[64 + tid] + asum_lds[128 + tid] + asum_lds[192 + tid];

    {
        ushort8 r0 = *reinterpret_cast<const ushort8*>(&Abuf[lane * 24]);
        ushort8 r1 = *reinterpret_cast<const ushort8*>(&Abuf[lane * 24 + 8]);
        unsigned short* dst = ws_a + ((size_t)n * KR + lane) * TP + t0w;
        *reinterpret_cast<ushort8*>(dst)     = r0;
        *reinterpret_cast<ushort8*>(dst + 8) = r1;
    }
}

// ---------------------------------------------------------------------------
// Kernel 2: GEMM2 (VLAD), R13 structure unchanged (fast: ~3-5 us).
// ---------------------------------------------------------------------------
#define LOADA(d0,d1,d2,d3,t0_)                                                   \
    d0 = *reinterpret_cast<const bf16x8*>(abase +           (size_t)(t0_));      \
    d1 = *reinterpret_cast<const bf16x8*>(abase + 16*TP +   (size_t)(t0_));      \
    d2 = *reinterpret_cast<const bf16x8*>(abase + 32*TP +   (size_t)(t0_));      \
    d3 = *reinterpret_cast<const bf16x8*>(abase + 48*TP +   (size_t)(t0_));

#define LOADB(d,t0_) do {                                                        \
    const int tb2_ = (t0_) + (lg << 3);                                          \
    if ((t0_) + 32 <= TT) {                                                      \
        _Pragma("unroll")                                                        \
        for (int j_ = 0; j_ < 8; ++j_)                                           \
            ((unsigned short*)&(d))[j_] = f2bf(gb[(size_t)(tb2_ + j_) * CCH]);   \
    } else {                                                                     \
        _Pragma("unroll")                                                        \
        for (int j_ = 0; j_ < 8; ++j_) {                                         \
            float v_ = (tb2_ + j_ < TT) ? gb[(size_t)(tb2_ + j_) * CCH] : 0.f;   \
            ((unsigned short*)&(d))[j_] = f2bf(v_);                              \
        }                                                                        \
    } } while (0)

__global__ __launch_bounds__(256, 4) void k_vlad(
    const float* __restrict__ grids,
    const unsigned short* __restrict__ ws_a,
    const float* __restrict__ ws_asum,
    const float* __restrict__ centroids,
    float* __restrict__ out)
{
    __shared__ float asum_s[64];

    const int tid  = threadIdx.x;
    const int lane = tid & 63;
    const int w    = tid >> 6;
    const int b    = (blockIdx.x & 7) * 96 + (blockIdx.x >> 3);
    const int n    = b / 12;
    const int c0   = (b - n * 12) << 6;
    const int lr   = lane & 15;
    const int lg   = lane >> 4;

    if (tid < 64) {
        float s = 0.f;
        #pragma unroll
        for (int bb = 0; bb < 10; ++bb)
            s += ws_asum[((size_t)n * 10 + bb) * 64 + tid];
        asum_s[tid] = s;
    }
    __syncthreads();

    const int c = c0 + (w << 4) + lr;
    const unsigned short* abase = ws_a + ((size_t)n * KR + lr) * TP + (lg << 3);
    const float* gb = grids + (size_t)n * TT * CCH + c;

    f32x4 acc0 = {}, acc1 = {}, acc2 = {}, acc3 = {};
    bf16x8 a0, a1, a2, a3, b0;
    bf16x8 p0, p1, p2, p3, q0;

    LOADA(a0, a1, a2, a3, 0)
    LOADB(b0, 0);

    int t0 = 0;
    while (true) {
        int tn = t0 + 32;
        if (tn < TT) { LOADA(p0, p1, p2, p3, tn) LOADB(q0, tn); }
        acc0 = __builtin_amdgcn_mfma_f32_16x16x32_bf16(a0, b0, acc0, 0, 0, 0);
        acc1 = __builtin_amdgcn_mfma_f32_16x16x32_bf16(a1, b0, acc1, 0, 0, 0);
        acc2 = __builtin_amdgcn_mfma_f32_16x16x32_bf16(a2, b0, acc2, 0, 0, 0);
        acc3 = __builtin_amdgcn_mfma_f32_16x16x32_bf16(a3, b0, acc3, 0, 0, 0);
        t0 = tn;
        if (t0 >= TT) break;

        tn = t0 + 32;
        if (tn < TT) { LOADA(a0, a1, a2, a3, tn) LOADB(b0, tn); }
        acc0 = __builtin_amdgcn_mfma_f32_16x16x32_bf16(p0, q0, acc0, 0, 0, 0);
        acc1 = __builtin_amdgcn_mfma_f32_16x16x32_bf16(p1, q0, acc1, 0, 0, 0);
        acc2 = __builtin_amdgcn_mfma_f32_16x16x32_bf16(p2, q0, acc2, 0, 0, 0);
        acc3 = __builtin_amdgcn_mfma_f32_16x16x32_bf16(p3, q0, acc3, 0, 0, 0);
        t0 = tn;
        if (t0 >= TT) break;
    }

    #pragma unroll
    for (int reg = 0; reg < 4; ++reg) {
        {
            const int kr = 0*16 + (lg << 2) + reg;
            out[((size_t)n * KR + kr) * CCH + c] =
                acc0[reg] - asum_s[kr] * centroids[(size_t)kr * CCH + c];
        }
        {
            const int kr = 1*16 + (lg << 2) + reg;
            out[((size_t)n * KR + kr) * CCH + c] =
                acc1[reg] - asum_s[kr] * centroids[(size_t)kr * CCH + c];
        }
        {
            const int kr = 2*16 + (lg << 2) + reg;
            out[((size_t)n * KR + kr) * CCH + c] =
                acc2[reg] - asum_s[kr] * centroids[(size_t)kr * CCH + c];
        }
        {
            const int kr = 3*16 + (lg << 2) + reg;
            out[((size_t)n * KR + kr) * CCH + c] =
                acc3[reg] - asum_s[kr] * centroids[(size_t)kr * CCH + c];
        }
    }
}

// ---------------------------------------------------------------------------
// Kernel 3: 4 rows per 256-thr block; global L2 norm of 64 unit rows = 8.
// ---------------------------------------------------------------------------
__global__ __launch_bounds__(256) void kc_norm_kernel(float* __restrict__ out)
{
    const int tid = threadIdx.x;
    const int sub = tid >> 6;
    const int l   = tid & 63;
    float4* p = reinterpret_cast<float4*>(out) + ((size_t)blockIdx.x * 4 + sub) * 192;
    float4 v0 = p[l];
    float4 v1 = p[l + 64];
    float4 v2 = p[l + 128];
    float ss = v0.x*v0.x + v0.y*v0.y + v0.z*v0.z + v0.w*v0.w
             + v1.x*v1.x + v1.y*v1.y + v1.z*v1.z + v1.w*v1.w
             + v2.x*v2.x + v2.y*v2.y + v2.z*v2.z + v2.w*v2.w;
    #pragma unroll
    for (int m = 1; m < 64; m <<= 1) ss += __shfl_xor(ss, m);
    const float sc = 0.125f / fmaxf(sqrtf(ss), EPSF);
    v0.x*=sc; v0.y*=sc; v0.z*=sc; v0.w*=sc;
    v1.x*=sc; v1.y*=sc; v1.z*=sc; v1.w*=sc;
    v2.x*=sc; v2.y*=sc; v2.z*=sc; v2.w*=sc;
    p[l] = v0;
    p[l + 64] = v1;
    p[l + 128] = v2;
}

extern "C" void kernel_launch(void* const* d_in, const int* in_sizes, int n_in,
                              void* d_out, int out_size, void* d_ws, size_t ws_size,
                              hipStream_t stream)
{
    const float* grids     = (const float*)d_in[0];
    const float* conv_w    = (const float*)d_in[1];
    const float* conv_b    = (const float*)d_in[2];
    const float* centroids = (const float*)d_in[3];
    float* out = (float*)d_out;

    // ws layout (bytes):
    //   ws_a    [0,         5,242,880)   64*64*640 bf16
    //   ws_asum [5,242,880, 5,406,720)   640*64 f32
    //   ws_w    [5,406,720, 5,505,024)   64*768 bf16
    unsigned short* ws_a    = (unsigned short*)d_ws;
    float*          ws_asum = (float*)((char*)d_ws + 5242880);
    unsigned short* ws_w    = (unsigned short*)((char*)d_ws + 5406720);

    hipLaunchKernelGGL(k_prep, dim3(24), dim3(256), 0, stream, conv_w, ws_w);
    hipLaunchKernelGGL(k_logits, dim3(NB * 10), dim3(256), 0, stream,
                       grids, ws_w, conv_b, ws_a, ws_asum);
    hipLaunchKernelGGL(k_vlad, dim3(NB * 12), dim3(256), 0, stream,
                       grids, ws_a, ws_asum, centroids, out);
    hipLaunchKernelGGL(kc_norm_kernel, dim3(NB * KR / 4), dim3(256), 0, stream, out);
}

// Round 18
// 71.366 us; speedup vs baseline: 1.4340x; 1.0705x over previous
//
#include <hip/hip_runtime.h>
#include <hip/hip_bf16.h>
#include <math.h>

#define TT 577          // real tokens per n
#define TP 640          // padded tokens per n
#define CCH 768         // channels
#define KR 64           // regions
#define NB 64           // batch

typedef __attribute__((ext_vector_type(8))) short bf16x8;
typedef __attribute__((ext_vector_type(8))) unsigned short ushort8;
typedef __attribute__((ext_vector_type(4))) float f32x4;

static constexpr float EPSF = 1e-12f;

// float -> bf16 bits via HW conversion (RNE)
static __device__ inline unsigned short f2bf(float f) {
    return __bfloat16_as_ushort(__float2bfloat16(f));
}

// ---------------------------------------------------------------------------
// Kernel 1 (best-measured R13 = R8 structure + XCD-chunked swizzle):
// GEMM1 + norm + softmax + a' transpose + partial asum.
// NOTE (session finding): total dur is dominated by the harness's 443-MB
// ws-poison fill running concurrently at ~7 TB/s (87-90% HBM peak); the
// reachable floor is (443 MB + our ~70 MB cold-miss traffic)/7 TB/s ~ 73 us.
// This kernel set measured 71.4 us - at that roofline.
// ---------------------------------------------------------------------------
__global__ __launch_bounds__(256, 3) void k_logits(
    const float* __restrict__ grids,
    const float* __restrict__ conv_w,
    const float* __restrict__ conv_b,
    unsigned short* __restrict__ ws_a,
    float* __restrict__ ws_asum)
{
    __shared__ __align__(16) unsigned short Wl[2][KR * 136];   // 2 x 17.4 KB

    const int tid  = threadIdx.x;
    const int lane = tid & 63;
    const int w    = tid >> 6;
    // XCD-chunked bijective swizzle: 640 = 8 XCD x 80 chunk
    const int b    = (blockIdx.x & 7) * 80 + (blockIdx.x >> 3);
    const int n    = b / 10;
    const int tb   = (b - n * 10) << 6;
    const int t0w  = tb + (w << 4);

    const int lr = lane & 15;
    const int lg = lane >> 4;

    const int tokA = t0w + lr;
    const bool validA = (tokA < TT);
    const float* gsrc = grids + ((size_t)n * TT + tokA) * CCH + (lg << 3);

    float4 wreg[4][2];
    auto load_w = [&](int c0) {
        #pragma unroll
        for (int it = 0; it < 4; ++it) {
            int f = tid + (it << 8);
            int kr = f >> 4, c8 = (f & 15) << 3;
            const float* src = conv_w + (size_t)kr * CCH + c0 + c8;
            wreg[it][0] = *reinterpret_cast<const float4*>(src);
            wreg[it][1] = *reinterpret_cast<const float4*>(src + 4);
        }
    };
    auto store_w = [&](int buf) {
        #pragma unroll
        for (int it = 0; it < 4; ++it) {
            int f = tid + (it << 8);
            int kr = f >> 4, c8 = (f & 15) << 3;
            ushort8 o;
            o[0] = f2bf(wreg[it][0].x); o[1] = f2bf(wreg[it][0].y);
            o[2] = f2bf(wreg[it][0].z); o[3] = f2bf(wreg[it][0].w);
            o[4] = f2bf(wreg[it][1].x); o[5] = f2bf(wreg[it][1].y);
            o[6] = f2bf(wreg[it][1].z); o[7] = f2bf(wreg[it][1].w);
            *reinterpret_cast<ushort8*>(&Wl[buf][kr * 136 + c8]) = o;
        }
    };

    f32x4 acc[4] = {};
    float ss = 0.f;

    load_w(0);
    store_w(0);
    __syncthreads();

    for (int ch = 0; ch < 6; ++ch) {
        if (ch < 5) {
            load_w((ch + 1) << 7);
            store_w((ch + 1) & 1);
        }
        const int c0 = ch << 7;
        const unsigned short* Wb = Wl[ch & 1];

        #pragma unroll
        for (int s = 0; s < 4; ++s) {
            float a8[8];
            if (validA) {
                float4 u0 = *reinterpret_cast<const float4*>(gsrc + c0 + (s << 5));
                float4 u1 = *reinterpret_cast<const float4*>(gsrc + c0 + (s << 5) + 4);
                a8[0]=u0.x; a8[1]=u0.y; a8[2]=u0.z; a8[3]=u0.w;
                a8[4]=u1.x; a8[5]=u1.y; a8[6]=u1.z; a8[7]=u1.w;
            } else {
                #pragma unroll
                for (int j = 0; j < 8; ++j) a8[j] = 0.f;
            }
            bf16x8 afrag;
            #pragma unroll
            for (int j = 0; j < 8; ++j) {
                ss = fmaf(a8[j], a8[j], ss);
                ((unsigned short*)&afrag)[j] = f2bf(a8[j]);
            }
            const int cl = (s << 5) + (lg << 3);
            #pragma unroll
            for (int rt = 0; rt < 4; ++rt) {
                bf16x8 bfrag = *reinterpret_cast<const bf16x8*>(&Wb[(rt*16 + lr)*136 + cl]);
                acc[rt] = __builtin_amdgcn_mfma_f32_16x16x32_bf16(afrag, bfrag, acc[rt], 0, 0, 0);
            }
        }

        __syncthreads();
    }

    // ---- token norm: reduce the 4 lg-groups of the same token ----
    ss += __shfl_xor(ss, 16);
    ss += __shfl_xor(ss, 32);
    const float nrm = sqrtf(ss);
    const float inv = 1.0f / fmaxf(nrm, EPSF);

    // ---- logits + softmax over 64 regions ----
    float b_[4];
    #pragma unroll
    for (int rt = 0; rt < 4; ++rt) b_[rt] = conv_b[rt*16 + lr];

    float invT[4];
    #pragma unroll
    for (int reg = 0; reg < 4; ++reg) invT[reg] = __shfl(inv, (lg << 2) + reg);

    float lgt[4][4], mx[4];
    #pragma unroll
    for (int reg = 0; reg < 4; ++reg) {
        float m = -1e30f;
        #pragma unroll
        for (int rt = 0; rt < 4; ++rt) {
            lgt[rt][reg] = fmaf(acc[rt][reg], invT[reg], b_[rt]);
            m = fmaxf(m, lgt[rt][reg]);
        }
        mx[reg] = m;
    }
    #pragma unroll
    for (int msk = 1; msk < 16; msk <<= 1) {
        #pragma unroll
        for (int reg = 0; reg < 4; ++reg) mx[reg] = fmaxf(mx[reg], __shfl_xor(mx[reg], msk));
    }
    float ex[4][4], sm[4] = {0.f, 0.f, 0.f, 0.f};
    #pragma unroll
    for (int rt = 0; rt < 4; ++rt) {
        #pragma unroll
        for (int reg = 0; reg < 4; ++reg) {
            ex[rt][reg] = __expf(lgt[rt][reg] - mx[reg]);
            sm[reg] += ex[rt][reg];
        }
    }
    #pragma unroll
    for (int msk = 1; msk < 16; msk <<= 1) {
        #pragma unroll
        for (int reg = 0; reg < 4; ++reg) sm[reg] += __shfl_xor(sm[reg], msk);
    }

    float rsm[4];
    #pragma unroll
    for (int reg = 0; reg < 4; ++reg) {
        const bool vt = (t0w + (lg << 2) + reg) < TT;
        rsm[reg] = vt ? (1.0f / sm[reg]) : 0.f;
    }

    // ---- per-block partial asum: pa[rt] holds kr = rt*16+lr ----
    float pa[4];
    #pragma unroll
    for (int rt = 0; rt < 4; ++rt) {
        pa[rt] = ex[rt][0]*rsm[0] + ex[rt][1]*rsm[1] + ex[rt][2]*rsm[2] + ex[rt][3]*rsm[3];
        pa[rt] += __shfl_xor(pa[rt], 16);
        pa[rt] += __shfl_xor(pa[rt], 32);
    }
    float* asum_lds = reinterpret_cast<float*>(&Wl[1][0]);   // [4 waves][64 kr]
    if (lane < 16) {
        #pragma unroll
        for (int rt = 0; rt < 4; ++rt)
            asum_lds[(w << 6) + rt*16 + lane] = pa[rt];
    }

    // ---- a' = softmax * inv_norm, transposed via LDS (aliased on Wl[0]) ----
    unsigned short* Abuf = &Wl[0][0] + (size_t)w * KR * 24;
    #pragma unroll
    for (int reg = 0; reg < 4; ++reg) {
        const int trow = (lg << 2) + reg;
        const float scale = invT[reg] * rsm[reg];
        #pragma unroll
        for (int rt = 0; rt < 4; ++rt)
            Abuf[(rt*16 + lr)*24 + trow] = f2bf(ex[rt][reg] * scale);
    }
    __syncthreads();

    if (tid < 64)
        ws_asum[(size_t)b * 64 + tid] =
            asum_lds[tid] + asum_lds[64 + tid] + asum_lds[128 + tid] + asum_lds[192 + tid];

    {
        ushort8 r0 = *reinterpret_cast<const ushort8*>(&Abuf[lane * 24]);
        ushort8 r1 = *reinterpret_cast<const ushort8*>(&Abuf[lane * 24 + 8]);
        unsigned short* dst = ws_a + ((size_t)n * KR + lane) * TP + t0w;
        *reinterpret_cast<ushort8*>(dst)     = r0;
        *reinterpret_cast<ushort8*>(dst + 8) = r1;
    }
}

// ---------------------------------------------------------------------------
// Kernel 2 (R13): all 12 c-tile blocks of an n land on ONE XCD -> grids
// slice shared in that XCD's L2/L3 (warm after k_logits). 768 = 8 x 96.
// ---------------------------------------------------------------------------
#define LOADA(d0,d1,d2,d3,t0_)                                                   \
    d0 = *reinterpret_cast<const bf16x8*>(abase +           (size_t)(t0_));      \
    d1 = *reinterpret_cast<const bf16x8*>(abase + 16*TP +   (size_t)(t0_));      \
    d2 = *reinterpret_cast<const bf16x8*>(abase + 32*TP +   (size_t)(t0_));      \
    d3 = *reinterpret_cast<const bf16x8*>(abase + 48*TP +   (size_t)(t0_));

#define LOADB(d,t0_) do {                                                        \
    const int tb2_ = (t0_) + (lg << 3);                                          \
    if ((t0_) + 32 <= TT) {                                                      \
        _Pragma("unroll")                                                        \
        for (int j_ = 0; j_ < 8; ++j_)                                           \
            ((unsigned short*)&(d))[j_] = f2bf(gb[(size_t)(tb2_ + j_) * CCH]);   \
    } else {                                                                     \
        _Pragma("unroll")                                                        \
        for (int j_ = 0; j_ < 8; ++j_) {                                         \
            float v_ = (tb2_ + j_ < TT) ? gb[(size_t)(tb2_ + j_) * CCH] : 0.f;   \
            ((unsigned short*)&(d))[j_] = f2bf(v_);                              \
        }                                                                        \
    } } while (0)

__global__ __launch_bounds__(256, 4) void k_vlad(
    const float* __restrict__ grids,
    const unsigned short* __restrict__ ws_a,
    const float* __restrict__ ws_asum,
    const float* __restrict__ centroids,
    float* __restrict__ out)
{
    __shared__ float asum_s[64];

    const int tid  = threadIdx.x;
    const int lane = tid & 63;
    const int w    = tid >> 6;
    // XCD-chunked bijective swizzle: 768 = 8 XCD x 96 chunk
    const int b    = (blockIdx.x & 7) * 96 + (blockIdx.x >> 3);
    const int n    = b / 12;
    const int c0   = (b - n * 12) << 6;
    const int lr   = lane & 15;
    const int lg   = lane >> 4;

    if (tid < 64) {
        float s = 0.f;
        #pragma unroll
        for (int bb = 0; bb < 10; ++bb)
            s += ws_asum[((size_t)n * 10 + bb) * 64 + tid];
        asum_s[tid] = s;
    }
    __syncthreads();

    const int c = c0 + (w << 4) + lr;
    const unsigned short* abase = ws_a + ((size_t)n * KR + lr) * TP + (lg << 3);
    const float* gb = grids + (size_t)n * TT * CCH + c;

    f32x4 acc0 = {}, acc1 = {}, acc2 = {}, acc3 = {};
    bf16x8 a0, a1, a2, a3, b0;
    bf16x8 p0, p1, p2, p3, q0;

    LOADA(a0, a1, a2, a3, 0)
    LOADB(b0, 0);

    int t0 = 0;
    while (true) {
        int tn = t0 + 32;
        if (tn < TT) { LOADA(p0, p1, p2, p3, tn) LOADB(q0, tn); }
        acc0 = __builtin_amdgcn_mfma_f32_16x16x32_bf16(a0, b0, acc0, 0, 0, 0);
        acc1 = __builtin_amdgcn_mfma_f32_16x16x32_bf16(a1, b0, acc1, 0, 0, 0);
        acc2 = __builtin_amdgcn_mfma_f32_16x16x32_bf16(a2, b0, acc2, 0, 0, 0);
        acc3 = __builtin_amdgcn_mfma_f32_16x16x32_bf16(a3, b0, acc3, 0, 0, 0);
        t0 = tn;
        if (t0 >= TT) break;

        tn = t0 + 32;
        if (tn < TT) { LOADA(a0, a1, a2, a3, tn) LOADB(b0, tn); }
        acc0 = __builtin_amdgcn_mfma_f32_16x16x32_bf16(p0, q0, acc0, 0, 0, 0);
        acc1 = __builtin_amdgcn_mfma_f32_16x16x32_bf16(p1, q0, acc1, 0, 0, 0);
        acc2 = __builtin_amdgcn_mfma_f32_16x16x32_bf16(p2, q0, acc2, 0, 0, 0);
        acc3 = __builtin_amdgcn_mfma_f32_16x16x32_bf16(p3, q0, acc3, 0, 0, 0);
        t0 = tn;
        if (t0 >= TT) break;
    }

    #pragma unroll
    for (int reg = 0; reg < 4; ++reg) {
        {
            const int kr = 0*16 + (lg << 2) + reg;
            out[((size_t)n * KR + kr) * CCH + c] =
                acc0[reg] - asum_s[kr] * centroids[(size_t)kr * CCH + c];
        }
        {
            const int kr = 1*16 + (lg << 2) + reg;
            out[((size_t)n * KR + kr) * CCH + c] =
                acc1[reg] - asum_s[kr] * centroids[(size_t)kr * CCH + c];
        }
        {
            const int kr = 2*16 + (lg << 2) + reg;
            out[((size_t)n * KR + kr) * CCH + c] =
                acc2[reg] - asum_s[kr] * centroids[(size_t)kr * CCH + c];
        }
        {
            const int kr = 3*16 + (lg << 2) + reg;
            out[((size_t)n * KR + kr) * CCH + c] =
                acc3[reg] - asum_s[kr] * centroids[(size_t)kr * CCH + c];
        }
    }
}

// ---------------------------------------------------------------------------
// Kernel 3: 4 rows per 256-thr block; global L2 norm of 64 unit rows = 8.
// ---------------------------------------------------------------------------
__global__ __launch_bounds__(256) void kc_norm_kernel(float* __restrict__ out)
{
    const int tid = threadIdx.x;
    const int sub = tid >> 6;
    const int l   = tid & 63;
    float4* p = reinterpret_cast<float4*>(out) + ((size_t)blockIdx.x * 4 + sub) * 192;
    float4 v0 = p[l];
    float4 v1 = p[l + 64];
    float4 v2 = p[l + 128];
    float ss = v0.x*v0.x + v0.y*v0.y + v0.z*v0.z + v0.w*v0.w
             + v1.x*v1.x + v1.y*v1.y + v1.z*v1.z + v1.w*v1.w
             + v2.x*v2.x + v2.y*v2.y + v2.z*v2.z + v2.w*v2.w;
    #pragma unroll
    for (int m = 1; m < 64; m <<= 1) ss += __shfl_xor(ss, m);
    const float sc = 0.125f / fmaxf(sqrtf(ss), EPSF);
    v0.x*=sc; v0.y*=sc; v0.z*=sc; v0.w*=sc;
    v1.x*=sc; v1.y*=sc; v1.z*=sc; v1.w*=sc;
    v2.x*=sc; v2.y*=sc; v2.z*=sc; v2.w*=sc;
    p[l] = v0;
    p[l + 64] = v1;
    p[l + 128] = v2;
}

extern "C" void kernel_launch(void* const* d_in, const int* in_sizes, int n_in,
                              void* d_out, int out_size, void* d_ws, size_t ws_size,
                              hipStream_t stream)
{
    const float* grids     = (const float*)d_in[0];
    const float* conv_w    = (const float*)d_in[1];
    const float* conv_b    = (const float*)d_in[2];
    const float* centroids = (const float*)d_in[3];
    float* out = (float*)d_out;

    // ws layout (bytes):
    //   ws_a    [0,         5,242,880)   64*64*640 bf16
    //   ws_asum [5,242,880, 5,406,720)   640*64 f32
    unsigned short* ws_a    = (unsigned short*)d_ws;
    float*          ws_asum = (float*)((char*)d_ws + 5242880);

    hipLaunchKernelGGL(k_logits, dim3(NB * 10), dim3(256), 0, stream,
                       grids, conv_w, conv_b, ws_a, ws_asum);
    hipLaunchKernelGGL(k_vlad, dim3(NB * 12), dim3(256), 0, stream,
                       grids, ws_a, ws_asum, centroids, out);
    hipLaunchKernelGGL(kc_norm_kernel, dim3(NB * KR / 4), dim3(256), 0, stream, out);
}